// Round 6
// baseline (329.497 us; speedup 1.0000x reference)
//
#include <hip/hip_runtime.h>
#include <math.h>

// ---- problem constants ----
#define BB 16
#define FD 32          // F == C == 32
#define ND 200
#define TD 48
#define SD 3
#define OC 64
#define SLICE 6400            // N*C elements per (b,t)
#define TSTRIDE 4915200       // B*T*N*C elements per tensor
#define NEGBIG (-9.0e15f)
#define LOG2E 1.44269504088896340736f

typedef __attribute__((ext_vector_type(8))) short bf16x8;
typedef __attribute__((ext_vector_type(4))) float f32x4;
typedef __attribute__((ext_vector_type(4))) unsigned int u32x4;

// round-half-up bf16 (within 1 ulp of RNE, 1 VALU op + shift)
static __device__ __forceinline__ unsigned short f2bf(float f) {
  unsigned u = __builtin_bit_cast(unsigned, f);
  return (unsigned short)((u + 0x8000u) >> 16);
}
// exact RNE (used for hi/lo weight split so the residual is well-defined)
static __device__ __forceinline__ unsigned short f2bf_rne(float f) {
  unsigned u = __builtin_bit_cast(unsigned, f);
  return (unsigned short)((u + 0x7FFFu + ((u >> 16) & 1u)) >> 16);
}
static __device__ __forceinline__ float bf2f(unsigned short h) {
  unsigned u = ((unsigned)h) << 16;
  return __builtin_bit_cast(float, u);
}

// packed f32 pair -> bf16 pair, round-half-up, BIT-IDENTICAL to f2bf().
// R9: v_cvt_pk_bf16_f32 turned out not to round RNE on gfx950 (R8 precision
// regression: absmax 0.016 -> 0.348, a systematic-truncation signature).
// This is 3 VALU ops/pair (add, add, v_perm) vs the old ~5-6.
static __device__ __forceinline__ unsigned int pk_bf16_rhu(float a, float b) {
  unsigned ua = __builtin_bit_cast(unsigned, a) + 0x8000u;
  unsigned ub = __builtin_bit_cast(unsigned, b) + 0x8000u;
#if __has_builtin(__builtin_amdgcn_perm)
  // result bytes = {ua.b2, ua.b3, ub.b2, ub.b3}  (low half = a, high = b)
  return __builtin_amdgcn_perm(ub, ua, 0x07060302u);
#else
  return (ua >> 16) | (ub & 0xFFFF0000u);
#endif
}

// hardware exp2 (v_exp_f32); inputs pre-scaled by LOG2E
#if __has_builtin(__builtin_amdgcn_exp2f)
static __device__ __forceinline__ float exp2_hw(float x) { return __builtin_amdgcn_exp2f(x); }
#else
static __device__ __forceinline__ float exp2_hw(float x) { return exp2f(x); }
#endif

// 1-ulp reciprocal (v_rcp_f32) — output feeds bf16 rounding, so the
// accuracy loss vs exact divide (2^-22 vs 2^-24) is invisible
#if __has_builtin(__builtin_amdgcn_rcpf)
static __device__ __forceinline__ float rcp_hw(float x) { return __builtin_amdgcn_rcpf(x); }
#else
static __device__ __forceinline__ float rcp_hw(float x) { return 1.0f / x; }
#endif

// sign-extend bit j of v to 0 / 0xFFFFFFFF (v_bfe_i32)
static __device__ __forceinline__ unsigned int sext_bit(unsigned int v, int j) {
#if __has_builtin(__builtin_amdgcn_sbfe)
  return (unsigned int)__builtin_amdgcn_sbfe((int)v, j, 1);
#else
  return 0u - ((v >> j) & 1u);
#endif
}

// merge low halfword of lo-mask with high halfword of hi-mask
static __device__ __forceinline__ unsigned int merge_hw(unsigned int lo, unsigned int hi) {
#if __has_builtin(__builtin_amdgcn_perm)
  return __builtin_amdgcn_perm(hi, lo, 0x07060100u);
#else
  return (lo & 0x0000FFFFu) | (hi & 0xFFFF0000u);
#endif
}

// One prep launch, three block ranges:
//   [0,3200):      x (b,f,n,t) fp32 -> Xtnc (b,t,n,c) bf16 + Xntc (b,n,t,c) bf16
//   [3200,3824):   adjacency -> permuted 200-bit row masks: per row 4 u64,
//                  qword qd holds bytes [k=0..6] = adjacency bits for
//                  m = k*32 + qd*8 + j  (one u64 load per 16-row tile later)
//   [3824,3976):   W transpose->bf16, w-vector hi/lo frags, mlp_w -> bf16
__global__ __launch_bounds__(256) void k_prep(
    const float* __restrict__ x, const int* __restrict__ support,
    const float* __restrict__ W1, const float* __restrict__ WK,
    const float* __restrict__ a1, const float* __restrict__ aK,
    const float* __restrict__ mw,
    unsigned short* __restrict__ Xtnc, unsigned short* __restrict__ Xntc,
    unsigned long long* __restrict__ msk,
    unsigned short* __restrict__ Wtb, unsigned short* __restrict__ Wxb,
    unsigned short* __restrict__ mwb) {
  __shared__ float sbuf[32 * 49];
  int bid = blockIdx.x;
  if (bid < 3200) {
    int b = bid / ND, n = bid % ND;
    float(*sf)[49] = (float(*)[49])sbuf;
    for (int i = threadIdx.x; i < 32 * 48; i += 256) {
      int f = i / 48, t = i % 48;
      sf[f][t] = x[((size_t)(b * 32 + f) * ND + n) * 48 + t];
    }
    __syncthreads();
    unsigned int* dt = (unsigned int*)Xtnc;
    unsigned int* dn = (unsigned int*)Xntc;
    for (int j = threadIdx.x; j < 768; j += 256) {
      int t = j >> 4, fq = j & 15;
      unsigned int v = (unsigned int)f2bf(sf[2 * fq][t]) |
                       ((unsigned int)f2bf(sf[2 * fq + 1][t]) << 16);
      dt[((size_t)(b * 48 + t) * ND + n) * 16 + fq] = v;
      dn[((size_t)(b * ND + n) * 48 + t) * 16 + fq] = v;
    }
  } else if (bid < 3824) {
    int q = bid - 3200;
    int si = q / 13, rg = q % 13;
    const int* adjb = support + (size_t)si * ND * ND;
    int wv = threadIdx.x >> 6, lane = threadIdx.x & 63;
#pragma unroll
    for (int j = 0; j < 4; j++) {
      int r = rg * 16 + wv * 4 + j;
      unsigned long long ws0 = 0, ws1 = 0, ws2 = 0, ws3 = 0;
      if (r < ND) {
        ws0 = __ballot(adjb[r * ND + lane] > 0);
        ws1 = __ballot(adjb[r * ND + 64 + lane] > 0);
        ws2 = __ballot(((128 + lane < ND) ? adjb[r * ND + 128 + lane] : 0) > 0);
        ws3 = __ballot(((192 + lane < ND) ? adjb[r * ND + 192 + lane] : 0) > 0);
      }
      // permute bytes: output qword qd, byte k  <-  straight byte (k*4+qd)
      if (lane < 4 && r < 208) {
        unsigned long long o = 0;
#pragma unroll
        for (int k = 0; k < 7; k++) {
          int bidx = k * 4 + lane;
          int sel = bidx >> 3;
          unsigned long long src = (sel == 0) ? ws0 : (sel == 1) ? ws1
                                 : (sel == 2) ? ws2 : ws3;
          unsigned long long byte = (src >> ((bidx & 7) * 8)) & 0xFFull;
          o |= byte << (8 * k);
        }
        msk[((size_t)si * 208 + r) * 4 + lane] = o;
      }
    }
  } else {
    int b2 = bid - 3824;
    if (b2 < 96) {
      int mat = b2 >> 4, b = b2 & 15;
      const float* src = (mat < 3) ? (W1 + (size_t)(mat * 16 + b) * 1024)
                                   : (WK + (size_t)((mat - 3) * 16 + b) * 1024);
      const float* av = (mat < 3) ? (a1 + (size_t)mat * 1024 + b * 64)
                                  : (aK + (size_t)(mat - 3) * 1024 + b * 64);
      unsigned short* dst = Wtb + (size_t)b2 * 1024;
      for (int i = threadIdx.x; i < 1024; i += 256) {
        int c = i >> 5, f = i & 31;
        dst[c * 32 + f] = f2bf_rne(src[f * 32 + c]);
      }
      // w-vectors: w1 = W@a1cols, w2 = W@a2cols (fp32), hi/lo bf16 split
      if (threadIdx.x < 32) {
        int f = threadIdx.x;
        float s1 = 0.f, s2 = 0.f;
        for (int c = 0; c < 32; c++) {
          float wfc = src[f * 32 + c];
          s1 = fmaf(wfc, av[c], s1);
          s2 = fmaf(wfc, av[32 + c], s2);
        }
        sbuf[f] = s1;
        sbuf[32 + f] = s2;
      }
      __syncthreads();
      unsigned short* wx = Wxb + (size_t)b2 * 512;  // [col][f], 16x32
      for (int i = threadIdx.x; i < 512; i += 256) {
        int col = i >> 5, f = i & 31;
        unsigned short o = 0;
        if (col < 4) {
          float s = sbuf[(col >> 1) * 32 + f];
          unsigned short hi = f2bf_rne(s);
          o = (col & 1) ? f2bf_rne(s - bf2f(hi)) : hi;
        }
        wx[i] = o;
      }
    } else {
      int i = (b2 - 96) * 256 + threadIdx.x;
      if (i < OC * 224) mwb[i] = f2bf_rne(mw[i]);
    }
  }
}

// Fused double-hop GAT per (idx,b,t). Wh + f1/f2 via MFMA (f1/f2 through an
// extra B-frag holding hi/lo split of W@a vectors -> fp32-accurate); attention
// P@V via MFMA with per-k A-frag build, denominator via ones-B MFMA.
// All-masked rows -> uniform 1/200 * colsum(V) (JAX softmax of all -9e15).
// Hop1 out staged in LDS for hop2.
// R13 (this round): OCCUPANCY ATTACK v2 — R12 established the allocator rule
//   arch_cap ~= 256/W for the 2nd launch_bounds arg (W=5->48, W=4->64,
//   W=2->128/used-120) and that occupancy stays pinned at ~2 waves/SIMD
//   (Occ ~21%) even at 120 arch VGPR => unified total (arch + accum AGPR)
//   exceeds 128. (256,3): arch cap ~85, budget 170 total, 12 waves/CU
//   (+50% TLP). Accumulators (24-32 regs) can shift to true AGPRs and the
//   scheduler can de-hoist LDS-read results to fit. SPILL SENTINEL:
//   WRITE_SIZE must stay 57,600 KB (R6/R7 spills added 450-940 MB).
//   Also reverted R12's uint2 f2e staging to R11's u32x4 (R12 cost +2.5us:
//   2x the LDS read instruction count).
// R11: FACTORIZED EXP — exp2(lrelu(x)) = max(exp2(x), exp2(0.2x)) factors
//   over x = f1+f2; per-row (E1,E1s) fp32 in f1e, per-col packed bf16
//   (E2<<16|E2s) in f2e. Attention per element: and/shl/mul/mul/max —
//   zero transcendentals. Masked elems AND'ed to +0.0 == exp(NEGBIG).
// R10: epilogue staged in Y1s, cooperative uint4 writeback; rcp_hw.
// R9: pk_bf16_rhu pack (v_cvt_pk_bf16_f32 is NOT RNE on gfx950 — R8 22x
//   precision regression); mask as AND on packed bf16 (sext+perm).
__global__ __launch_bounds__(256, 3) void k_gat2(
    const unsigned short* __restrict__ Xb,   // (b,t,n,c) bf16 (padded alloc)
    const unsigned short* __restrict__ Wtb,  // 6 mats: [mat][b][c][f] bf16
    const unsigned short* __restrict__ Wxb,  // 6 mats: [mat][b][16][32] bf16
    const unsigned char* __restrict__ mskb,  // (b*SD+idx)*208*32 B, permuted
    unsigned short* __restrict__ bfp) {      // 7-tensor bf16 (b,n,t,c) pool
  int bx = blockIdx.x;
  int idx = bx / (BB * TD);
  int bt = bx % (BB * TD);
  int b = bt / TD, t = bt % TD;
  __shared__ __align__(16) unsigned short Vt[32 * 232];   // [ch][m] pad->232
  __shared__ __align__(16) unsigned short Y1s[208 * 32];  // hop out [n][c]
  __shared__ __align__(16) unsigned int f2e[224];  // packed bf16 (E2<<16|E2s)
  __shared__ __align__(16) float2 f1e[208];        // (E1, E1s) fp32
  __shared__ float SVa[64];   // [0..31] hop1 colsum, [32..63] hop2
  int tid = threadIdx.x, w = tid >> 6, lane = tid & 63;
  int cl = lane & 15, qd = lane >> 4;

  // ---- init pads ----
  if (tid < 64) SVa[tid] = 0.f;
  for (int i = tid; i < 512; i += 256) {  // Vt[:][200..231] = 0
    int cch = i >> 4, d = i & 15;
    ((unsigned int*)&Vt[cch * 232 + 200])[d] = 0u;
  }
  for (int i = tid; i < 128; i += 256)    // Y1s rows 200..207 = 0
    ((unsigned int*)&Y1s[200 * 32])[i] = 0u;
  __syncthreads();

  const unsigned char* mrow = mskb + (size_t)(b * SD + idx) * 208 * 32;
  size_t xbase = (size_t)bt * SLICE;
  unsigned short* Yb1 = bfp + (size_t)(1 + 2 * idx) * TSTRIDE;
  unsigned short* Yb2 = bfp + (size_t)(2 + 2 * idx) * TSTRIDE;
  const float C1 = LOG2E;           // log2(e)
  const float C2 = 0.2f * LOG2E;    // alpha * log2(e)

#pragma unroll 1
  for (int hop = 0; hop < 2; hop++) {
    int mat = (hop == 0) ? idx : (3 + idx);
    const unsigned short* wtb = Wtb + (size_t)(mat * 16 + b) * 1024;
    const unsigned short* wxb = Wxb + (size_t)(mat * 16 + b) * 512;
    bf16x8 Bw0 = *(const bf16x8*)(wtb + cl * 32 + qd * 8);
    bf16x8 Bw1 = *(const bf16x8*)(wtb + (cl + 16) * 32 + qd * 8);
    bf16x8 Bwx = *(const bf16x8*)(wxb + cl * 32 + qd * 8);
    float* SV = SVa + hop * 32;

    // ---- Wh phase ----
    for (int ti = w; ti < 13; ti += 4) {
      bf16x8 A;
      if (hop == 0)
        A = *(const bf16x8*)(Xb + xbase + (size_t)(ti * 16 + cl) * 32 + qd * 8);
      else
        A = *(const bf16x8*)&Y1s[(ti * 16 + cl) * 32 + qd * 8];
      f32x4 d0 = {0.f, 0.f, 0.f, 0.f}, d1 = d0, d2 = d0;
      d0 = __builtin_amdgcn_mfma_f32_16x16x32_bf16(A, Bw0, d0, 0, 0, 0);
      d1 = __builtin_amdgcn_mfma_f32_16x16x32_bf16(A, Bw1, d1, 0, 0, 0);
      d2 = __builtin_amdgcn_mfma_f32_16x16x32_bf16(A, Bwx, d2, 0, 0, 0);
      int rn0 = ti * 16 + qd * 4;
      float s0 = 0.f, s1 = 0.f;
#pragma unroll
      for (int r = 0; r < 4; r++) {
        float fv = d2[r] + __shfl_xor(d2[r], 1, 64);  // cl0:f1, cl2:f2
        int rn = rn0 + r;
        if (rn < ND) {
          s0 += d0[r];
          s1 += d1[r];
          float E = exp2_hw(fv * C1);    // exp2(L*f)
          float Es = exp2_hw(fv * C2);   // exp2(0.2*L*f)
          if (cl == 0) f1e[rn] = make_float2(E, Es);
          if (cl == 2) f2e[rn] = pk_bf16_rhu(Es, E);  // low=Es, high=E
        }
      }
      if (rn0 + 3 < ND) {  // quads never straddle n=200 (200 % 4 == 0)
        uint2 q0, q1;
        q0.x = pk_bf16_rhu(d0[0], d0[1]);
        q0.y = pk_bf16_rhu(d0[2], d0[3]);
        q1.x = pk_bf16_rhu(d1[0], d1[1]);
        q1.y = pk_bf16_rhu(d1[2], d1[3]);
        *(uint2*)&Vt[cl * 232 + rn0] = q0;
        *(uint2*)&Vt[(cl + 16) * 232 + rn0] = q1;
      }
      atomicAdd(&SV[cl], s0);
      atomicAdd(&SV[cl + 16], s1);
    }
    __syncthreads();

    // ---- attention phase ----
    for (int ti = w; ti < 13; ti += 4) {
      int row = ti * 16 + cl;
      float2 e1p = f1e[row];
      float E1 = e1p.x, E1s = e1p.y;
      // one u64: byte k = adjacency bits for m = k*32 + qd*8 + j
      const unsigned long long mq =
          *(const unsigned long long*)(mrow + (size_t)row * 32 + qd * 8);
      f32x4 denom = {0.f, 0.f, 0.f, 0.f};
      f32x4 acc0 = denom, acc1 = denom;
      bf16x8 ones;
#pragma unroll
      for (int j = 0; j < 8; j++) ones[j] = (short)0x3F80;  // bf16 1.0
#pragma unroll
      for (int k = 0; k < 7; k++) {
        int m0 = k * 32 + qd * 8;
        bf16x8 b0 = *(const bf16x8*)&Vt[cl * 232 + m0];
        bf16x8 b1 = *(const bf16x8*)&Vt[(cl + 16) * 232 + m0];
        u32x4 ua = *(const u32x4*)&f2e[m0];
        u32x4 ub = *(const u32x4*)&f2e[m0 + 4];
        unsigned int mby = (unsigned int)(mq >> (8 * k)) & 0xFFu;
        u32x4 aw;
#pragma unroll
        for (int p = 0; p < 4; p++) {
          unsigned int u0 = (p < 2) ? ((p & 1) ? ua.z : ua.x)
                                    : ((p & 1) ? ub.z : ub.x);
          unsigned int u1 = (p < 2) ? ((p & 1) ? ua.w : ua.y)
                                    : ((p & 1) ? ub.w : ub.y);
          // P = max(E1*E2, E1s*E2s); E2 in high half (AND), E2s low (SHL)
          float p0 = fmaxf(E1 * __builtin_bit_cast(float, u0 & 0xFFFF0000u),
                           E1s * __builtin_bit_cast(float, u0 << 16));
          float p1 = fmaxf(E1 * __builtin_bit_cast(float, u1 & 0xFFFF0000u),
                           E1s * __builtin_bit_cast(float, u1 << 16));
          unsigned int pk = pk_bf16_rhu(p0, p1);
          unsigned int mlo = sext_bit(mby, 2 * p);
          unsigned int mhi = sext_bit(mby, 2 * p + 1);
          aw[p] = pk & merge_hw(mlo, mhi);        // masked lanes -> +0.0 bf16
        }
        bf16x8 A = __builtin_bit_cast(bf16x8, aw);
        denom = __builtin_amdgcn_mfma_f32_16x16x32_bf16(A, ones, denom, 0, 0, 0);
        acc0 = __builtin_amdgcn_mfma_f32_16x16x32_bf16(A, b0, acc0, 0, 0, 0);
        acc1 = __builtin_amdgcn_mfma_f32_16x16x32_bf16(A, b1, acc1, 0, 0, 0);
      }
#pragma unroll
      for (int r = 0; r < 4; r++) {
        int rn = ti * 16 + qd * 4 + r;
        if (rn < ND) {
          float dn = denom[r];
          float v0, v1;
          if (dn > 0.f) {
            float iv = rcp_hw(dn);
            v0 = acc0[r] * iv;
            v1 = acc1[r] * iv;
          } else {
            v0 = SV[cl] * (1.0f / ND);
            v1 = SV[cl + 16] * (1.0f / ND);
          }
          if (hop == 0) {
            v0 = (v0 > 0.f) ? v0 : exp2_hw(v0 * LOG2E) - 1.f;  // elu
            v1 = (v1 > 0.f) ? v1 : exp2_hw(v1 * LOG2E) - 1.f;
          } else {
            v0 = fmaxf(v0, 0.f);  // relu (== relu(elu(h)))
            v1 = fmaxf(v1, 0.f);
          }
          Y1s[rn * 32 + cl] = f2bf(v0);
          Y1s[rn * 32 + cl + 16] = f2bf(v1);
        }
      }
    }
    __syncthreads();
    // ---- cooperative coalesced writeback: Y1s rows 0..199 -> global ----
    {
      unsigned short* Yb = (hop == 0) ? Yb1 : Yb2;
      for (int i = tid; i < 800; i += 256) {
        int rn = i >> 2, part = i & 3;
        uint4 vq = *(const uint4*)&Y1s[rn * 32 + part * 8];
        *(uint4*)(Yb + ((size_t)(b * ND + rn) * TD + t) * 32 + part * 8) = vq;
      }
    }
    // hop0 -> hop1 needs no extra barrier: hop1-Wh reads Y1s (stable) and
    // writes Vt/f1e/f2e, which no wave touches after the barrier above.
  }
}

// 1x1 conv as MFMA GEMM per (b,n): OUT[t,o] = H[t,c] @ mw^T[c,o].
__global__ __launch_bounds__(192) void k_conv(
    const unsigned short* __restrict__ hb,   // 7 bf16 (b,n,t,c), stride TSTRIDE
    const unsigned short* __restrict__ mwb,  // (64,224) bf16
    const float* __restrict__ mb,
    float* __restrict__ out) {
  int bn = blockIdx.x;
  int b = bn / ND, n = bn % ND;
  int w = threadIdx.x >> 6, lane = threadIdx.x & 63;
  int cl = lane & 15, qd = lane >> 4;
  int mt = w;  // M-tile (t-range mt*16..mt*16+15)
  size_t abase = ((size_t)(b * ND + n) * TD + mt * 16 + cl) * 32 + qd * 8;
  bf16x8 A[7];
#pragma unroll
  for (int k = 0; k < 7; k++)
    A[k] = *(const bf16x8*)(hb + (size_t)k * TSTRIDE + abase);
#pragma unroll
  for (int nt = 0; nt < 4; nt++) {
    f32x4 acc = {0.f, 0.f, 0.f, 0.f};
#pragma unroll
    for (int k = 0; k < 7; k++) {
      bf16x8 bw = *(const bf16x8*)(mwb + (size_t)(nt * 16 + cl) * 224 + k * 32 + qd * 8);
      acc = __builtin_amdgcn_mfma_f32_16x16x32_bf16(A[k], bw, acc, 0, 0, 0);
    }
    int o = nt * 16 + cl;
    float bias = mb[o];
    float4 st;
    st.x = acc[0] + bias;
    st.y = acc[1] + bias;
    st.z = acc[2] + bias;
    st.w = acc[3] + bias;
    *(float4*)(out + ((size_t)(b * OC + o) * ND + n) * TD + mt * 16 + qd * 4) = st;
  }
}

extern "C" void kernel_launch(void* const* d_in, const int* in_sizes, int n_in,
                              void* d_out, int out_size, void* d_ws, size_t ws_size,
                              hipStream_t stream) {
  const float* x = (const float*)d_in[0];
  const int* support = (const int*)d_in[1];
  const float* W1 = (const float*)d_in[2];
  const float* a1 = (const float*)d_in[3];
  const float* WK = (const float*)d_in[4];
  const float* aK = (const float*)d_in[5];
  const float* mw = (const float*)d_in[6];
  const float* mb = (const float*)d_in[7];
  float* out = (float*)d_out;
  char* wsb = (char*)d_ws;
  // ws layout (bytes):
  //   Xbt bf16 (b,t,n,c) +1KB pad  @ 0            9,831,424
  //   bfp 7x bf16 (b,n,t,c)        @  9,831,424  68,812,800
  //   msk 48*208*32 B              @ 78,644,224     319,488
  //   mwb bf16                     @ 78,963,712      28,672
  //   Wtb 6*16*1024 bf16           @ 78,992,384     196,608
  //   Wxb 6*16*512  bf16           @ 79,188,992      98,304   => ~79.3 MB
  unsigned short* Xbt = (unsigned short*)wsb;
  unsigned short* bfp = (unsigned short*)(wsb + 9831424);
  unsigned char* msk = (unsigned char*)(wsb + 78644224);
  unsigned short* mwb = (unsigned short*)(wsb + 78963712);
  unsigned short* Wtb = (unsigned short*)(wsb + 78992384);
  unsigned short* Wxb = (unsigned short*)(wsb + 79188992);

  k_prep<<<3976, 256, 0, stream>>>(x, support, W1, WK, a1, aK, mw, Xbt, bfp,
                                   (unsigned long long*)msk, Wtb, Wxb, mwb);
  k_gat2<<<SD * BB * TD, 256, 0, stream>>>(Xbt, Wtb, Wxb, msk, bfp);
  k_conv<<<BB * ND, 192, 0, stream>>>(bfp, mwb, mb, out);
}

// Round 7
// 238.820 us; speedup vs baseline: 1.3797x; 1.3797x over previous
//
#include <hip/hip_runtime.h>
#include <math.h>

// ---- problem constants ----
#define BB 16
#define FD 32          // F == C == 32
#define ND 200
#define TD 48
#define SD 3
#define OC 64
#define SLICE 6400            // N*C elements per (b,t)
#define TSTRIDE 4915200       // B*T*N*C elements per tensor
#define NEGBIG (-9.0e15f)
#define LOG2E 1.44269504088896340736f

typedef __attribute__((ext_vector_type(8))) short bf16x8;
typedef __attribute__((ext_vector_type(4))) float f32x4;
typedef __attribute__((ext_vector_type(4))) unsigned int u32x4;

// round-half-up bf16 (within 1 ulp of RNE, 1 VALU op + shift)
static __device__ __forceinline__ unsigned short f2bf(float f) {
  unsigned u = __builtin_bit_cast(unsigned, f);
  return (unsigned short)((u + 0x8000u) >> 16);
}
// exact RNE (used for hi/lo weight split so the residual is well-defined)
static __device__ __forceinline__ unsigned short f2bf_rne(float f) {
  unsigned u = __builtin_bit_cast(unsigned, f);
  return (unsigned short)((u + 0x7FFFu + ((u >> 16) & 1u)) >> 16);
}
static __device__ __forceinline__ float bf2f(unsigned short h) {
  unsigned u = ((unsigned)h) << 16;
  return __builtin_bit_cast(float, u);
}

// packed f32 pair -> bf16 pair, round-half-up, BIT-IDENTICAL to f2bf().
// R9: v_cvt_pk_bf16_f32 is NOT RNE on gfx950 (R8 precision regression).
static __device__ __forceinline__ unsigned int pk_bf16_rhu(float a, float b) {
  unsigned ua = __builtin_bit_cast(unsigned, a) + 0x8000u;
  unsigned ub = __builtin_bit_cast(unsigned, b) + 0x8000u;
#if __has_builtin(__builtin_amdgcn_perm)
  // result bytes = {ua.b2, ua.b3, ub.b2, ub.b3}  (low half = a, high = b)
  return __builtin_amdgcn_perm(ub, ua, 0x07060302u);
#else
  return (ua >> 16) | (ub & 0xFFFF0000u);
#endif
}

// hardware exp2 (v_exp_f32); inputs pre-scaled by LOG2E
#if __has_builtin(__builtin_amdgcn_exp2f)
static __device__ __forceinline__ float exp2_hw(float x) { return __builtin_amdgcn_exp2f(x); }
#else
static __device__ __forceinline__ float exp2_hw(float x) { return exp2f(x); }
#endif

// 1-ulp reciprocal (v_rcp_f32) — feeds bf16 rounding, loss invisible
#if __has_builtin(__builtin_amdgcn_rcpf)
static __device__ __forceinline__ float rcp_hw(float x) { return __builtin_amdgcn_rcpf(x); }
#else
static __device__ __forceinline__ float rcp_hw(float x) { return 1.0f / x; }
#endif

// sign-extend bit j of v to 0 / 0xFFFFFFFF (v_bfe_i32)
static __device__ __forceinline__ unsigned int sext_bit(unsigned int v, int j) {
#if __has_builtin(__builtin_amdgcn_sbfe)
  return (unsigned int)__builtin_amdgcn_sbfe((int)v, j, 1);
#else
  return 0u - ((v >> j) & 1u);
#endif
}

// merge low halfword of lo-mask with high halfword of hi-mask
static __device__ __forceinline__ unsigned int merge_hw(unsigned int lo, unsigned int hi) {
#if __has_builtin(__builtin_amdgcn_perm)
  return __builtin_amdgcn_perm(hi, lo, 0x07060100u);
#else
  return (lo & 0x0000FFFFu) | (hi & 0xFFFF0000u);
#endif
}

// One prep launch, three block ranges (R14 layout):
//   [0,800):       x (b,f,n,t) fp32 -> Xtnc (b,t,n,c) + Xntc (b,n,t,c) bf16,
//                  4 n per block: float4 loads (4x fewer instr), bf16 LDS
//                  staging (12.4 KB, stride-194 rows), dt writes now 256-B
//                  contiguous runs per t (was 64-B scatter), dn 3-KB runs.
//   [800,1424):    adjacency -> permuted 200-bit row masks (unchanged)
//   [1424,1576):   W transpose->bf16, w-vector frags, mlp_w -> bf16
__global__ __launch_bounds__(256) void k_prep(
    const float* __restrict__ x, const int* __restrict__ support,
    const float* __restrict__ W1, const float* __restrict__ WK,
    const float* __restrict__ a1, const float* __restrict__ aK,
    const float* __restrict__ mw,
    unsigned short* __restrict__ Xtnc, unsigned short* __restrict__ Xntc,
    unsigned long long* __restrict__ msk,
    unsigned short* __restrict__ Wtb, unsigned short* __restrict__ Wxb,
    unsigned short* __restrict__ mwb) {
  __shared__ float sbuf[3104];  // 12.4 KB: x-stage (bf16 32x194) / w-vectors
  int bid = blockIdx.x;
  if (bid < 800) {
    int b = bid / 50, n0 = (bid % 50) * 4;
    unsigned short* sf16 = (unsigned short*)sbuf;  // [f][col], stride 194
    const float4* xv = (const float4*)x;
    for (int i = threadIdx.x; i < 1536; i += 256) {
      int nn = i / 384, rem = i % 384, f = rem / 12, q = rem % 12;
      float4 v = xv[(size_t)((b * 32 + f) * ND + n0 + nn) * 12 + q];
      unsigned short* p = &sf16[f * 194 + nn * 48 + 4 * q];
      p[0] = f2bf(v.x);
      p[1] = f2bf(v.y);
      p[2] = f2bf(v.z);
      p[3] = f2bf(v.w);
    }
    __syncthreads();
    unsigned int* dt = (unsigned int*)Xtnc;
    unsigned int* dn = (unsigned int*)Xntc;
    // pass 1: dt (b,t,n,c) — fq fast, nn mid, t slow -> 256-B runs per t
    for (int j = threadIdx.x; j < 3072; j += 256) {
      int t = j >> 6, rem = j & 63, nn = rem >> 4, fq = rem & 15;
      int col = nn * 48 + t;
      unsigned int v = (unsigned int)sf16[(2 * fq) * 194 + col] |
                       ((unsigned int)sf16[(2 * fq + 1) * 194 + col] << 16);
      dt[((size_t)(b * 48 + t) * ND + n0 + nn) * 16 + fq] = v;
    }
    // pass 2: dn (b,n,t,c) — fq fast, t mid, nn slow -> 3-KB runs per nn
    for (int j = threadIdx.x; j < 3072; j += 256) {
      int nn = j / 768, rem = j % 768, t = rem >> 4, fq = rem & 15;
      int col = nn * 48 + t;
      unsigned int v = (unsigned int)sf16[(2 * fq) * 194 + col] |
                       ((unsigned int)sf16[(2 * fq + 1) * 194 + col] << 16);
      dn[((size_t)(b * ND + n0 + nn) * 48 + t) * 16 + fq] = v;
    }
  } else if (bid < 1424) {
    int q = bid - 800;
    int si = q / 13, rg = q % 13;
    const int* adjb = support + (size_t)si * ND * ND;
    int wv = threadIdx.x >> 6, lane = threadIdx.x & 63;
#pragma unroll
    for (int j = 0; j < 4; j++) {
      int r = rg * 16 + wv * 4 + j;
      unsigned long long ws0 = 0, ws1 = 0, ws2 = 0, ws3 = 0;
      if (r < ND) {
        ws0 = __ballot(adjb[r * ND + lane] > 0);
        ws1 = __ballot(adjb[r * ND + 64 + lane] > 0);
        ws2 = __ballot(((128 + lane < ND) ? adjb[r * ND + 128 + lane] : 0) > 0);
        ws3 = __ballot(((192 + lane < ND) ? adjb[r * ND + 192 + lane] : 0) > 0);
      }
      // permute bytes: output qword qd, byte k  <-  straight byte (k*4+qd)
      if (lane < 4 && r < 208) {
        unsigned long long o = 0;
#pragma unroll
        for (int k = 0; k < 7; k++) {
          int bidx = k * 4 + lane;
          int sel = bidx >> 3;
          unsigned long long src = (sel == 0) ? ws0 : (sel == 1) ? ws1
                                 : (sel == 2) ? ws2 : ws3;
          unsigned long long byte = (src >> ((bidx & 7) * 8)) & 0xFFull;
          o |= byte << (8 * k);
        }
        msk[((size_t)si * 208 + r) * 4 + lane] = o;
      }
    }
  } else {
    int b2 = bid - 1424;
    if (b2 < 96) {
      int mat = b2 >> 4, b = b2 & 15;
      const float* src = (mat < 3) ? (W1 + (size_t)(mat * 16 + b) * 1024)
                                   : (WK + (size_t)((mat - 3) * 16 + b) * 1024);
      const float* av = (mat < 3) ? (a1 + (size_t)mat * 1024 + b * 64)
                                  : (aK + (size_t)(mat - 3) * 1024 + b * 64);
      unsigned short* dst = Wtb + (size_t)b2 * 1024;
      for (int i = threadIdx.x; i < 1024; i += 256) {
        int c = i >> 5, f = i & 31;
        dst[c * 32 + f] = f2bf_rne(src[f * 32 + c]);
      }
      // w-vectors: w1 = W@a1cols, w2 = W@a2cols (fp32), hi/lo bf16 split
      if (threadIdx.x < 32) {
        int f = threadIdx.x;
        float s1 = 0.f, s2 = 0.f;
        for (int c = 0; c < 32; c++) {
          float wfc = src[f * 32 + c];
          s1 = fmaf(wfc, av[c], s1);
          s2 = fmaf(wfc, av[32 + c], s2);
        }
        sbuf[f] = s1;
        sbuf[32 + f] = s2;
      }
      __syncthreads();
      unsigned short* wx = Wxb + (size_t)b2 * 512;  // [col][f], 16x32
      for (int i = threadIdx.x; i < 512; i += 256) {
        int col = i >> 5, f = i & 31;
        unsigned short o = 0;
        if (col < 4) {
          float s = sbuf[(col >> 1) * 32 + f];
          unsigned short hi = f2bf_rne(s);
          o = (col & 1) ? f2bf_rne(s - bf2f(hi)) : hi;
        }
        wx[i] = o;
      }
    } else {
      int i = (b2 - 96) * 256 + threadIdx.x;
      if (i < OC * 224) mwb[i] = f2bf_rne(mw[i]);
    }
  }
}

// Fused double-hop GAT per (idx,b,t) — R11 configuration verbatim (131 us).
// R13 post-mortem: (256,3) cap -> 84 VGPR + 245 MB spill (WRITE_SIZE
// sentinel fired), 216 us despite Occ 31%. Bracketing: true live set in
// (85,120] arch regs -> no cap reaches the 4-wave bin without spilling.
// The register-cap path is CLOSED; 120-reg/2-wave is this structure's
// optimum. Do NOT add a 2nd __launch_bounds__ arg.
// R11: FACTORIZED EXP — exp2(lrelu(x)) = max(exp2(x), exp2(0.2x)) factors
//   over x = f1+f2; per-row (E1,E1s) fp32 in f1e, per-col packed bf16
//   (E2<<16|E2s) in f2e. Attention per element: and/shl/mul/mul/max —
//   zero transcendentals. Masked elems AND'ed to +0.0 == exp(NEGBIG).
// R10: epilogue staged in Y1s, cooperative uint4 writeback; rcp_hw.
// R9: pk_bf16_rhu pack (v_cvt_pk_bf16_f32 is NOT RNE on gfx950).
__global__ __launch_bounds__(256) void k_gat2(
    const unsigned short* __restrict__ Xb,   // (b,t,n,c) bf16 (padded alloc)
    const unsigned short* __restrict__ Wtb,  // 6 mats: [mat][b][c][f] bf16
    const unsigned short* __restrict__ Wxb,  // 6 mats: [mat][b][16][32] bf16
    const unsigned char* __restrict__ mskb,  // (b*SD+idx)*208*32 B, permuted
    unsigned short* __restrict__ bfp) {      // 7-tensor bf16 (b,n,t,c) pool
  int bx = blockIdx.x;
  int idx = bx / (BB * TD);
  int bt = bx % (BB * TD);
  int b = bt / TD, t = bt % TD;
  __shared__ __align__(16) unsigned short Vt[32 * 232];   // [ch][m] pad->232
  __shared__ __align__(16) unsigned short Y1s[208 * 32];  // hop out [n][c]
  __shared__ __align__(16) unsigned int f2e[224];  // packed bf16 (E2<<16|E2s)
  __shared__ __align__(16) float2 f1e[208];        // (E1, E1s) fp32
  __shared__ float SVa[64];   // [0..31] hop1 colsum, [32..63] hop2
  int tid = threadIdx.x, w = tid >> 6, lane = tid & 63;
  int cl = lane & 15, qd = lane >> 4;

  // ---- init pads ----
  if (tid < 64) SVa[tid] = 0.f;
  for (int i = tid; i < 512; i += 256) {  // Vt[:][200..231] = 0
    int cch = i >> 4, d = i & 15;
    ((unsigned int*)&Vt[cch * 232 + 200])[d] = 0u;
  }
  for (int i = tid; i < 128; i += 256)    // Y1s rows 200..207 = 0
    ((unsigned int*)&Y1s[200 * 32])[i] = 0u;
  __syncthreads();

  const unsigned char* mrow = mskb + (size_t)(b * SD + idx) * 208 * 32;
  bf16x8 ones;
#pragma unroll
  for (int j = 0; j < 8; j++) ones[j] = (short)0x3F80;  // bf16 1.0
  size_t xbase = (size_t)bt * SLICE;
  unsigned short* Yb1 = bfp + (size_t)(1 + 2 * idx) * TSTRIDE;
  unsigned short* Yb2 = bfp + (size_t)(2 + 2 * idx) * TSTRIDE;
  const float C1 = LOG2E;           // log2(e)
  const float C2 = 0.2f * LOG2E;    // alpha * log2(e)

#pragma unroll
  for (int hop = 0; hop < 2; hop++) {
    int mat = (hop == 0) ? idx : (3 + idx);
    const unsigned short* wtb = Wtb + (size_t)(mat * 16 + b) * 1024;
    const unsigned short* wxb = Wxb + (size_t)(mat * 16 + b) * 512;
    bf16x8 Bw0 = *(const bf16x8*)(wtb + cl * 32 + qd * 8);
    bf16x8 Bw1 = *(const bf16x8*)(wtb + (cl + 16) * 32 + qd * 8);
    bf16x8 Bwx = *(const bf16x8*)(wxb + cl * 32 + qd * 8);
    float* SV = SVa + hop * 32;

    // ---- Wh phase ----
    for (int ti = w; ti < 13; ti += 4) {
      bf16x8 A;
      if (hop == 0)
        A = *(const bf16x8*)(Xb + xbase + (size_t)(ti * 16 + cl) * 32 + qd * 8);
      else
        A = *(const bf16x8*)&Y1s[(ti * 16 + cl) * 32 + qd * 8];
      f32x4 d0 = {0.f, 0.f, 0.f, 0.f}, d1 = d0, d2 = d0;
      d0 = __builtin_amdgcn_mfma_f32_16x16x32_bf16(A, Bw0, d0, 0, 0, 0);
      d1 = __builtin_amdgcn_mfma_f32_16x16x32_bf16(A, Bw1, d1, 0, 0, 0);
      d2 = __builtin_amdgcn_mfma_f32_16x16x32_bf16(A, Bwx, d2, 0, 0, 0);
      int rn0 = ti * 16 + qd * 4;
      float s0 = 0.f, s1 = 0.f;
#pragma unroll
      for (int r = 0; r < 4; r++) {
        float fv = d2[r] + __shfl_xor(d2[r], 1, 64);  // cl0:f1, cl2:f2
        int rn = rn0 + r;
        if (rn < ND) {
          s0 += d0[r];
          s1 += d1[r];
          float E = exp2_hw(fv * C1);    // exp2(L*f)
          float Es = exp2_hw(fv * C2);   // exp2(0.2*L*f)
          if (cl == 0) f1e[rn] = make_float2(E, Es);
          if (cl == 2) f2e[rn] = pk_bf16_rhu(Es, E);  // low=Es, high=E
        }
      }
      if (rn0 + 3 < ND) {  // quads never straddle n=200 (200 % 4 == 0)
        uint2 q0, q1;
        q0.x = pk_bf16_rhu(d0[0], d0[1]);
        q0.y = pk_bf16_rhu(d0[2], d0[3]);
        q1.x = pk_bf16_rhu(d1[0], d1[1]);
        q1.y = pk_bf16_rhu(d1[2], d1[3]);
        *(uint2*)&Vt[cl * 232 + rn0] = q0;
        *(uint2*)&Vt[(cl + 16) * 232 + rn0] = q1;
      }
      atomicAdd(&SV[cl], s0);
      atomicAdd(&SV[cl + 16], s1);
    }
    __syncthreads();

    // ---- attention phase ----
    for (int ti = w; ti < 13; ti += 4) {
      int row = ti * 16 + cl;
      float2 e1p = f1e[row];
      float E1 = e1p.x, E1s = e1p.y;
      // one u64: byte k = adjacency bits for m = k*32 + qd*8 + j
      const unsigned long long mq =
          *(const unsigned long long*)(mrow + (size_t)row * 32 + qd * 8);
      f32x4 denom = {0.f, 0.f, 0.f, 0.f};
      f32x4 acc0 = denom, acc1 = denom;
#pragma unroll
      for (int k = 0; k < 7; k++) {
        int m0 = k * 32 + qd * 8;
        bf16x8 b0 = *(const bf16x8*)&Vt[cl * 232 + m0];
        bf16x8 b1 = *(const bf16x8*)&Vt[(cl + 16) * 232 + m0];
        u32x4 ua = *(const u32x4*)&f2e[m0];
        u32x4 ub = *(const u32x4*)&f2e[m0 + 4];
        unsigned int mby = (unsigned int)(mq >> (8 * k)) & 0xFFu;
        u32x4 aw;
#pragma unroll
        for (int p = 0; p < 4; p++) {
          unsigned int u0 = (p < 2) ? ((p & 1) ? ua.z : ua.x)
                                    : ((p & 1) ? ub.z : ub.x);
          unsigned int u1 = (p < 2) ? ((p & 1) ? ua.w : ua.y)
                                    : ((p & 1) ? ub.w : ub.y);
          // P = max(E1*E2, E1s*E2s); E2 in high half (AND), E2s low (SHL)
          float p0 = fmaxf(E1 * __builtin_bit_cast(float, u0 & 0xFFFF0000u),
                           E1s * __builtin_bit_cast(float, u0 << 16));
          float p1 = fmaxf(E1 * __builtin_bit_cast(float, u1 & 0xFFFF0000u),
                           E1s * __builtin_bit_cast(float, u1 << 16));
          unsigned int pk = pk_bf16_rhu(p0, p1);
          unsigned int mlo = sext_bit(mby, 2 * p);
          unsigned int mhi = sext_bit(mby, 2 * p + 1);
          aw[p] = pk & merge_hw(mlo, mhi);        // masked lanes -> +0.0 bf16
        }
        bf16x8 A = __builtin_bit_cast(bf16x8, aw);
        denom = __builtin_amdgcn_mfma_f32_16x16x32_bf16(A, ones, denom, 0, 0, 0);
        acc0 = __builtin_amdgcn_mfma_f32_16x16x32_bf16(A, b0, acc0, 0, 0, 0);
        acc1 = __builtin_amdgcn_mfma_f32_16x16x32_bf16(A, b1, acc1, 0, 0, 0);
      }
#pragma unroll
      for (int r = 0; r < 4; r++) {
        int rn = ti * 16 + qd * 4 + r;
        if (rn < ND) {
          float dn = denom[r];
          float v0, v1;
          if (dn > 0.f) {
            float iv = rcp_hw(dn);
            v0 = acc0[r] * iv;
            v1 = acc1[r] * iv;
          } else {
            v0 = SV[cl] * (1.0f / ND);
            v1 = SV[cl + 16] * (1.0f / ND);
          }
          if (hop == 0) {
            v0 = (v0 > 0.f) ? v0 : exp2_hw(v0 * LOG2E) - 1.f;  // elu
            v1 = (v1 > 0.f) ? v1 : exp2_hw(v1 * LOG2E) - 1.f;
          } else {
            v0 = fmaxf(v0, 0.f);  // relu (== relu(elu(h)))
            v1 = fmaxf(v1, 0.f);
          }
          Y1s[rn * 32 + cl] = f2bf(v0);
          Y1s[rn * 32 + cl + 16] = f2bf(v1);
        }
      }
    }
    __syncthreads();
    // ---- cooperative coalesced writeback: Y1s rows 0..199 -> global ----
    {
      unsigned short* Yb = (hop == 0) ? Yb1 : Yb2;
      for (int i = tid; i < 800; i += 256) {
        int rn = i >> 2, part = i & 3;
        uint4 vq = *(const uint4*)&Y1s[rn * 32 + part * 8];
        *(uint4*)(Yb + ((size_t)(b * ND + rn) * TD + t) * 32 + part * 8) = vq;
      }
    }
    // hop0 -> hop1 needs no extra barrier: hop1-Wh reads Y1s (stable) and
    // writes Vt/f1e/f2e, which no wave touches after the barrier above.
  }
}

// 1x1 conv as MFMA GEMM. R14: wave = nt (o-tile); each wave loads its 7
// B-frags ONCE into registers (was 12 reloads/block -> 268 MB cache
// traffic), loops mt x 2n. Grid 1600 x 256, ~50 VGPR (8 waves/SIMD).
__global__ __launch_bounds__(256) void k_conv(
    const unsigned short* __restrict__ hb,   // 7 bf16 (b,n,t,c), stride TSTRIDE
    const unsigned short* __restrict__ mwb,  // (64,224) bf16
    const float* __restrict__ mb,
    float* __restrict__ out) {
  int bn = blockIdx.x;               // 16 * 100
  int b = bn / 100, n0 = (bn % 100) * 2;
  int w = threadIdx.x >> 6, lane = threadIdx.x & 63;
  int cl = lane & 15, qd = lane >> 4;
  // wave w owns output o-tile [w*16, w*16+16)
  bf16x8 bw[7];
#pragma unroll
  for (int k = 0; k < 7; k++)
    bw[k] = *(const bf16x8*)(mwb + (size_t)(w * 16 + cl) * 224 + k * 32 + qd * 8);
  int o = w * 16 + cl;
  float bias = mb[o];
#pragma unroll
  for (int nn = 0; nn < 2; nn++) {
    int n = n0 + nn;
#pragma unroll
    for (int mt = 0; mt < 3; mt++) {
      size_t abase = ((size_t)(b * ND + n) * TD + mt * 16 + cl) * 32 + qd * 8;
      f32x4 acc = {0.f, 0.f, 0.f, 0.f};
#pragma unroll
      for (int k = 0; k < 7; k++) {
        bf16x8 A = *(const bf16x8*)(hb + (size_t)k * TSTRIDE + abase);
        acc = __builtin_amdgcn_mfma_f32_16x16x32_bf16(A, bw[k], acc, 0, 0, 0);
      }
      float4 st;
      st.x = acc[0] + bias;
      st.y = acc[1] + bias;
      st.z = acc[2] + bias;
      st.w = acc[3] + bias;
      *(float4*)(out + ((size_t)(b * OC + o) * ND + n) * TD + mt * 16 + qd * 4) = st;
    }
  }
}

extern "C" void kernel_launch(void* const* d_in, const int* in_sizes, int n_in,
                              void* d_out, int out_size, void* d_ws, size_t ws_size,
                              hipStream_t stream) {
  const float* x = (const float*)d_in[0];
  const int* support = (const int*)d_in[1];
  const float* W1 = (const float*)d_in[2];
  const float* a1 = (const float*)d_in[3];
  const float* WK = (const float*)d_in[4];
  const float* aK = (const float*)d_in[5];
  const float* mw = (const float*)d_in[6];
  const float* mb = (const float*)d_in[7];
  float* out = (float*)d_out;
  char* wsb = (char*)d_ws;
  // ws layout (bytes):
  //   Xbt bf16 (b,t,n,c) +1KB pad  @ 0            9,831,424
  //   bfp 7x bf16 (b,n,t,c)        @  9,831,424  68,812,800
  //   msk 48*208*32 B              @ 78,644,224     319,488
  //   mwb bf16                     @ 78,963,712      28,672
  //   Wtb 6*16*1024 bf16           @ 78,992,384     196,608
  //   Wxb 6*16*512  bf16           @ 79,188,992      98,304   => ~79.3 MB
  unsigned short* Xbt = (unsigned short*)wsb;
  unsigned short* bfp = (unsigned short*)(wsb + 9831424);
  unsigned char* msk = (unsigned char*)(wsb + 78644224);
  unsigned short* mwb = (unsigned short*)(wsb + 78963712);
  unsigned short* Wtb = (unsigned short*)(wsb + 78992384);
  unsigned short* Wxb = (unsigned short*)(wsb + 79188992);

  k_prep<<<1576, 256, 0, stream>>>(x, support, W1, WK, a1, aK, mw, Xbt, bfp,
                                   (unsigned long long*)msk, Wtb, Wxb, mwb);
  k_gat2<<<SD * BB * TD, 256, 0, stream>>>(Xbt, Wtb, Wxb, msk, bfp);
  k_conv<<<BB * 100, 256, 0, stream>>>(bfp, mwb, mb, out);
}